// Round 1
// baseline (1537.508 us; speedup 1.0000x reference)
//
#include <hip/hip_runtime.h>

#define N_NODES 25000
#define N_EDGES 400000

static constexpr float INV_SQRT3 = 0.5773502691896257f;
static constexpr float PW0 = 0.20412414523193154f;   // sqrt(1/24)
static constexpr float PW1 = 0.35355339059327373f;   // sqrt(3/24)
static constexpr float SILU_NORM = 1.6791767923989418f;

// Accumulate NC consecutive W2 columns (base points at column c0 of row 0):
// w[i] = sum_k h[k] * W2[k*576 + c0 + i].  All addresses are wave-uniform ->
// scalar-load eligible; W2 is L2-resident (147 KB).
template <int NC>
__device__ __forceinline__ void gemm_cols(const float* __restrict__ base,
                                          const float (&h)[64], float (&w)[NC]) {
#pragma unroll
    for (int i = 0; i < NC; ++i) w[i] = 0.f;
#pragma unroll
    for (int k = 0; k < 64; ++k) {
        const float4* r4 = (const float4*)(base + k * 576);
        const float hk = h[k];
#pragma unroll
        for (int q = 0; q < NC / 4; ++q) {
            float4 a = r4[q];
            w[q * 4 + 0] += hk * a.x;
            w[q * 4 + 1] += hk * a.y;
            w[q * 4 + 2] += hk * a.z;
            w[q * 4 + 3] += hk * a.w;
        }
    }
}

__global__ __launch_bounds__(256) void conv_fused(
    const float* __restrict__ node_input,
    const int* __restrict__ edge_src,
    const int* __restrict__ edge_dst,
    const float* __restrict__ edge_attr,
    const float* __restrict__ dist_embedding,
    const float* __restrict__ W1,
    const float* __restrict__ W2,
    float* __restrict__ out)
{
    // per-thread private x-slot; stride 44 floats (176 B) keeps float4 alignment
    __shared__ float sX[256 * 44];
    const int e = blockIdx.x * 256 + threadIdx.x;
    if (e >= N_EDGES) return;
    float* xs = &sX[threadIdx.x * 44];

    // ---------------- GEMM1: z = d @ W1 (z[k] = sum_j d_j W1[j,k]) ----------
    float z[64];
#pragma unroll
    for (int k = 0; k < 64; ++k) z[k] = 0.f;
    const float4* dp = (const float4*)(dist_embedding + (size_t)e * 64);
#pragma unroll 2
    for (int j4 = 0; j4 < 16; ++j4) {
        float4 d4 = dp[j4];
        float dj[4] = {d4.x, d4.y, d4.z, d4.w};
#pragma unroll
        for (int r = 0; r < 4; ++r) {
            const float4* w1r = (const float4*)(W1 + (j4 * 4 + r) * 64);
            const float dv = dj[r];
#pragma unroll
            for (int k4 = 0; k4 < 16; ++k4) {
                float4 a = w1r[k4];
                z[k4 * 4 + 0] += dv * a.x;
                z[k4 * 4 + 1] += dv * a.y;
                z[k4 * 4 + 2] += dv * a.z;
                z[k4 * 4 + 3] += dv * a.w;
            }
        }
    }

    // silu: h = SILU_NORM * silu(z/8)
    float h[64];
#pragma unroll
    for (int k = 0; k < 64; ++k) {
        const float zz = 0.125f * z[k];
        h[k] = SILU_NORM * __fdividef(zz, 1.f + __expf(-zz));
    }

    // ------------- gather x (to private LDS slot) and y (regs) -------------
    const int dst = edge_dst[e];
    const float4* xr = (const float4*)(node_input + (size_t)dst * 40);
    float4* xd = (float4*)xs;
#pragma unroll
    for (int i = 0; i < 10; ++i) xd[i] = xr[i];

    const float4 yv = *(const float4*)(edge_attr + (size_t)e * 4);
    const float y0 = yv.x, y1x = yv.y, y1y = yv.z, y1z = yv.w;

    // coefficient prefactors; 1/32 folds GEMM2's 1/sqrt(64) and final 1/sqrt(16)
    const float SC = 0.03125f;
    const float q0 = PW0 * y0 * SC;
    const float q4 = PW0 * INV_SQRT3 * SC;
    const float kP1 = PW1 * INV_SQRT3 * SC;
    const float q20 = kP1 * y1x, q21 = kP1 * y1y, q22 = kP1 * y1z;
    const float q3 = kP1 * y0;

    float o0[16], o1[24];
#pragma unroll
    for (int i = 0; i < 16; ++i) o0[i] = 0.f;
#pragma unroll
    for (int i = 0; i < 24; ++i) o1[i] = 0.f;

    // ---------------- GEMM2 + tensor product, fused per region -------------
    // Region 1: w1[u,wo] at cols u*16+wo; out0[wo] += PW0*x0[u]*y0 * w
#pragma unroll 1
    for (int u = 0; u < 16; ++u) {
        float w[16];
        gemm_cols<16>(W2 + u * 16, h, w);
        const float coef = q0 * xs[u];
#pragma unroll
        for (int i = 0; i < 16; ++i) o0[i] += coef * w[i];
    }
    // Region 2: w2[u,wo] at 256+u*8+wo; out1[wo,j] += K*x0[u]*y1[j] * w
#pragma unroll 1
    for (int u = 0; u < 16; ++u) {
        float w[8];
        gemm_cols<8>(W2 + 256 + u * 8, h, w);
        const float xv = xs[u];
        const float c0 = q20 * xv, c1 = q21 * xv, c2 = q22 * xv;
#pragma unroll
        for (int i = 0; i < 8; ++i) {
            o1[i * 3 + 0] += c0 * w[i];
            o1[i * 3 + 1] += c1 * w[i];
            o1[i * 3 + 2] += c2 * w[i];
        }
    }
    // Region 3: w3[u,wo] at 384+u*8+wo; out1[wo,j] += K*x1[u,j]*y0 * w
#pragma unroll 1
    for (int u = 0; u < 8; ++u) {
        float w[8];
        gemm_cols<8>(W2 + 384 + u * 8, h, w);
        const float c0 = q3 * xs[16 + u * 3 + 0];
        const float c1 = q3 * xs[16 + u * 3 + 1];
        const float c2 = q3 * xs[16 + u * 3 + 2];
#pragma unroll
        for (int i = 0; i < 8; ++i) {
            o1[i * 3 + 0] += c0 * w[i];
            o1[i * 3 + 1] += c1 * w[i];
            o1[i * 3 + 2] += c2 * w[i];
        }
    }
    // Region 4: w4[u,wo] at 448+u*16+wo; out0[wo] += PW0*c3*(x1[u].y1) * w
#pragma unroll 1
    for (int u = 0; u < 8; ++u) {
        float w[16];
        gemm_cols<16>(W2 + 448 + u * 16, h, w);
        const float b = q4 * (xs[16 + u * 3 + 0] * y1x +
                              xs[16 + u * 3 + 1] * y1y +
                              xs[16 + u * 3 + 2] * y1z);
#pragma unroll
        for (int i = 0; i < 16; ++i) o0[i] += b * w[i];
    }

    // ---------------- scatter-add to out[src] -------------------------------
    const int src = edge_src[e];
    float* op = out + (size_t)src * 40;
#pragma unroll
    for (int i = 0; i < 16; ++i) atomicAdd(op + i, o0[i]);
#pragma unroll
    for (int i = 0; i < 24; ++i) atomicAdd(op + 16 + i, o1[i]);
}

extern "C" void kernel_launch(void* const* d_in, const int* in_sizes, int n_in,
                              void* d_out, int out_size, void* d_ws, size_t ws_size,
                              hipStream_t stream)
{
    const float* node_input     = (const float*)d_in[0];
    const int*   edge_src       = (const int*)d_in[1];
    const int*   edge_dst       = (const int*)d_in[2];
    const float* edge_attr      = (const float*)d_in[3];
    const float* dist_embedding = (const float*)d_in[4];
    const float* W1             = (const float*)d_in[5];
    const float* W2             = (const float*)d_in[6];
    float* out = (float*)d_out;

    hipMemsetAsync(out, 0, (size_t)out_size * sizeof(float), stream);
    dim3 grid((N_EDGES + 255) / 256);
    conv_fused<<<grid, 256, 0, stream>>>(node_input, edge_src, edge_dst,
                                         edge_attr, dist_embedding, W1, W2, out);
}